// Round 5
// baseline (849.503 us; speedup 1.0000x reference)
//
#include <hip/hip_runtime.h>
#include <hip/hip_fp16.h>
#include <math.h>

#define NN 500000
#define NE 5000000
#define K_B 1954                  // dst buckets of 256 nodes
#define SB 8                      // src bins (s>>16)
#define NBINS (K_B * SB)          // 15632
#define NBP 250                   // partition blocks
#define EPB 20000                 // edges per partition block (NBP*EPB == NE)
#define M_SCAN (NBINS * NBP)      // 3,908,000
#define SC_CH 4096                // scan chunk: 256 thr * 16
#define NB_SC 955                 // ceil(M_SCAN / SC_CH)
#define M_PAD (NB_SC * SC_CH)     // 3,911,680

__device__ inline float2 cvt2(unsigned u) {
    __half2 h = *reinterpret_cast<const __half2*>(&u);
    return __half22float2(h);
}

// ================= partition by (dst_bucket, src_bin) — no global atomics =================

__global__ __launch_bounds__(1024) void pass1_count(
    const int* __restrict__ ei, int* __restrict__ counts)
{
    __shared__ int lh[NBINS];
    for (int i = threadIdx.x; i < NBINS; i += 1024) lh[i] = 0;
    __syncthreads();
    int e0 = blockIdx.x * EPB;
    for (int k = threadIdx.x; k < EPB; k += 1024) {
        int e = e0 + k;
        int s = ei[e];
        int d = ei[NE + e];
        atomicAdd(&lh[(d >> 8) * SB + (s >> 16)], 1);
    }
    __syncthreads();
    for (int i = threadIdx.x; i < NBINS; i += 1024)
        counts[i * NBP + blockIdx.x] = lh[i];
}

__global__ __launch_bounds__(256) void scan_reduce(
    const int* __restrict__ a, int* __restrict__ partial)
{
    __shared__ int sm[256];
    int base = blockIdx.x * SC_CH + threadIdx.x * 16;
    int s = 0;
#pragma unroll
    for (int k = 0; k < 16; ++k) s += a[base + k];
    sm[threadIdx.x] = s;
    __syncthreads();
    for (int off = 128; off > 0; off >>= 1) {
        if (threadIdx.x < off) sm[threadIdx.x] += sm[threadIdx.x + off];
        __syncthreads();
    }
    if (threadIdx.x == 0) partial[blockIdx.x] = sm[0];
}

__global__ __launch_bounds__(256) void scan_mid(int* __restrict__ partial)
{
    __shared__ int sm[256];
    int t = threadIdx.x;
    int v[4]; int s = 0;
#pragma unroll
    for (int k = 0; k < 4; ++k) {
        int i = t * 4 + k;
        v[k] = (i < NB_SC) ? partial[i] : 0;
        s += v[k];
    }
    sm[t] = s;
    __syncthreads();
    int orig = s;
    for (int off = 1; off < 256; off <<= 1) {
        int u = (t >= off) ? sm[t - off] : 0;
        __syncthreads();
        sm[t] += u;
        __syncthreads();
    }
    int run = sm[t] - orig;   // exclusive base for this thread's 4
#pragma unroll
    for (int k = 0; k < 4; ++k) {
        int i = t * 4 + k;
        if (i < NB_SC) partial[i] = run;
        run += v[k];
    }
}

__global__ __launch_bounds__(256) void scan_apply(
    int* __restrict__ a, const int* __restrict__ partial)
{
    __shared__ int sm[256];
    int b = blockIdx.x, t = threadIdx.x;
    int base = b * SC_CH + t * 16;
    int v[16]; int s = 0;
#pragma unroll
    for (int k = 0; k < 16; ++k) { v[k] = a[base + k]; s += v[k]; }
    sm[t] = s;
    __syncthreads();
    int orig = s;
    for (int off = 1; off < 256; off <<= 1) {
        int u = (t >= off) ? sm[t - off] : 0;
        __syncthreads();
        sm[t] += u;
        __syncthreads();
    }
    int run = partial[b] + sm[t] - orig;
#pragma unroll
    for (int k = 0; k < 16; ++k) { a[base + k] = run; run += v[k]; }
}

__global__ __launch_bounds__(1024) void pass2_scatter(
    const int* __restrict__ ei, const int* __restrict__ counts,
    unsigned int* __restrict__ sorted)
{
    __shared__ int cur[NBINS];
    for (int i = threadIdx.x; i < NBINS; i += 1024)
        cur[i] = counts[i * NBP + blockIdx.x];
    __syncthreads();
    int e0 = blockIdx.x * EPB;
    for (int k = threadIdx.x; k < EPB; k += 1024) {
        int e = e0 + k;
        int s = ei[e];
        int d = ei[NE + e];
        int bin = (d >> 8) * SB + (s >> 16);
        int pos = atomicAdd(&cur[bin], 1);   // LDS atomic
        sorted[pos] = ((unsigned)(d & 255) << 20) | (unsigned)s;
    }
}

// ================= node-side projection (fp16 output) =================

__global__ __launch_bounds__(256) void proj1(
    const float* __restrict__ x, const float* __restrict__ w,
    const float* __restrict__ b, __half* __restrict__ h1)
{
    int i = blockIdx.x * 256 + threadIdx.x;
    if (i >= NN) return;
    float x0 = x[i*3+0], x1 = x[i*3+1], x2 = x[i*3+2];
    __half hh[4];
#pragma unroll
    for (int j = 0; j < 3; ++j) {
        float v = fmaf(x0, w[0*3+j], fmaf(x1, w[1*3+j], fmaf(x2, w[2*3+j], b[j])));
        hh[j] = __float2half(v > 0.f ? v : 0.f);
    }
    hh[3] = __float2half(0.f);
    *reinterpret_cast<uint2*>(h1 + (size_t)i * 4) = *reinterpret_cast<uint2*>(hh);
}

// ================= layer kernels: one 512-thread block per 256-node bucket =================

__global__ __launch_bounds__(512, 8) void layer1_kernel(
    const int* __restrict__ counts, const unsigned int* __restrict__ sorted,
    const __half* __restrict__ h1, const float* __restrict__ x,
    const float* __restrict__ l1w, const float* __restrict__ l1b,
    const float* __restrict__ r1w,
    const float* __restrict__ p2w, const float* __restrict__ p2b,
    float* __restrict__ X2, __half* __restrict__ H2)
{
    __shared__ float acc[256][5];   // stride 5: banks spread
    __shared__ float slw[48], srw[48], slb[16], sp2w[256], sp2b[16];
    int t = threadIdx.x, b = blockIdx.x;
    if (t < 256) {
        sp2w[t] = p2w[t];
        if (t < 48) { slw[t] = l1w[t]; srw[t] = r1w[t]; }
        if (t < 16) { slb[t] = l1b[t]; sp2b[t] = p2b[t]; }
        acc[t][0] = 0.f; acc[t][1] = 0.f; acc[t][2] = 0.f;
    }
    __syncthreads();
    int beg = counts[(b * SB) * NBP];
    int end = (b == K_B - 1) ? NE : counts[((b + 1) * SB) * NBP];
    int a0 = beg & ~3;
    for (int c = a0 + t * 4; c < end; c += 2048) {
        uint4 sv = *reinterpret_cast<const uint4*>(sorted + c);
        const unsigned* svp = &sv.x;
        uint2 hr[4]; int dl[4]; bool ok[4];
#pragma unroll
        for (int j = 0; j < 4; ++j) {
            int e = c + j;
            unsigned v = svp[j];
            ok[j] = (e >= beg) && (e < end);
            int s = ok[j] ? (int)(v & 0xFFFFFu) : 0;
            dl[j] = (int)(v >> 20);
            hr[j] = *reinterpret_cast<const uint2*>(h1 + (size_t)s * 4);
        }
#pragma unroll
        for (int j = 0; j < 4; ++j) if (ok[j]) {
            float2 ab = cvt2(hr[j].x);
            float2 cd = cvt2(hr[j].y);
            atomicAdd(&acc[dl[j]][0], ab.x);
            atomicAdd(&acc[dl[j]][1], ab.y);
            atomicAdd(&acc[dl[j]][2], cd.x);
        }
    }
    __syncthreads();
    if (t >= 256) return;
    int node = (b << 8) + t;
    if (node >= NN) return;
    float a0v = acc[t][0], a1 = acc[t][1], a2 = acc[t][2];
    float x0 = x[node*3+0], x1 = x[node*3+1], x2v = x[node*3+2];
    float h[16];
#pragma unroll
    for (int j = 0; j < 16; ++j) {
        float v = slb[j];
        v = fmaf(a0v, slw[j], fmaf(a1, slw[16+j], fmaf(a2, slw[32+j], v)));
        v = fmaf(x0, srw[j], fmaf(x1, srw[16+j], fmaf(x2v, srw[32+j], v)));
        h[j] = v > 0.f ? v : 0.f;
    }
    float4* xp = reinterpret_cast<float4*>(X2 + (size_t)node * 16);
#pragma unroll
    for (int q = 0; q < 4; ++q)
        xp[q] = make_float4(h[q*4+0], h[q*4+1], h[q*4+2], h[q*4+3]);
    __half hh[16];
#pragma unroll
    for (int j = 0; j < 16; ++j) {
        float v = sp2b[j];
#pragma unroll
        for (int k = 0; k < 16; ++k) v = fmaf(h[k], sp2w[k*16+j], v);
        hh[j] = __float2half(v > 0.f ? v : 0.f);
    }
    uint4* hp = reinterpret_cast<uint4*>(H2 + (size_t)node * 16);
    hp[0] = reinterpret_cast<uint4*>(hh)[0];
    hp[1] = reinterpret_cast<uint4*>(hh)[1];
}

__global__ __launch_bounds__(512, 8) void layer2_kernel(
    const int* __restrict__ counts, const unsigned int* __restrict__ sorted,
    const __half* __restrict__ H2, float* X /* x2 in, x3 out */,
    const float* __restrict__ l2w, const float* __restrict__ l2b,
    const float* __restrict__ r2w,
    const float* __restrict__ p3w, const float* __restrict__ p3b,
    const float* __restrict__ l3w, __half* __restrict__ g)
{
    __shared__ float acc[256][17];
    __shared__ float slw[256], srw[256], sp3w[256];
    __shared__ float slb[16], sp3b[16], sl3w[16];
    int t = threadIdx.x, b = blockIdx.x;
    if (t < 256) {
        slw[t] = l2w[t]; srw[t] = r2w[t]; sp3w[t] = p3w[t];
        if (t < 16) { slb[t] = l2b[t]; sp3b[t] = p3b[t]; sl3w[t] = l3w[t]; }
#pragma unroll
        for (int k = 0; k < 17; ++k) acc[t][k] = 0.f;
    }
    __syncthreads();
    int beg = counts[(b * SB) * NBP];
    int end = (b == K_B - 1) ? NE : counts[((b + 1) * SB) * NBP];
    int pr = t >> 1, p = t & 1;
    int a0 = beg & ~3;
    int kbase = p * 8;
    for (int c = a0 + pr * 4; c < end; c += 1024) {
        uint4 sv = *reinterpret_cast<const uint4*>(sorted + c);
        const unsigned* svp = &sv.x;
        uint4 hr[4]; int dl[4]; bool ok[4];
#pragma unroll
        for (int j = 0; j < 4; ++j) {
            int e = c + j;
            unsigned v = svp[j];
            ok[j] = (e >= beg) && (e < end);
            int s = ok[j] ? (int)(v & 0xFFFFFu) : 0;
            dl[j] = (int)(v >> 20);
            hr[j] = *reinterpret_cast<const uint4*>(H2 + (size_t)s * 16 + kbase);
        }
#pragma unroll
        for (int j = 0; j < 4; ++j) if (ok[j]) {
            float2 f0 = cvt2(hr[j].x), f1 = cvt2(hr[j].y);
            float2 f2 = cvt2(hr[j].z), f3 = cvt2(hr[j].w);
            float* ap = &acc[dl[j]][kbase];
            atomicAdd(ap + 0, f0.x); atomicAdd(ap + 1, f0.y);
            atomicAdd(ap + 2, f1.x); atomicAdd(ap + 3, f1.y);
            atomicAdd(ap + 4, f2.x); atomicAdd(ap + 5, f2.y);
            atomicAdd(ap + 6, f3.x); atomicAdd(ap + 7, f3.y);
        }
    }
    __syncthreads();
    if (t >= 256) return;
    int node = (b << 8) + t;
    if (node >= NN) return;
    float av[16], xv[16];
#pragma unroll
    for (int k = 0; k < 16; ++k) av[k] = acc[t][k];
    const float4* xp = reinterpret_cast<const float4*>(X + (size_t)node * 16);
#pragma unroll
    for (int qq = 0; qq < 4; ++qq) {
        float4 u = xp[qq];
        xv[qq*4+0] = u.x; xv[qq*4+1] = u.y; xv[qq*4+2] = u.z; xv[qq*4+3] = u.w;
    }
    float o[16];
#pragma unroll
    for (int j = 0; j < 16; ++j) {
        float v = slb[j];
#pragma unroll
        for (int k = 0; k < 16; ++k) v = fmaf(av[k], slw[k*16+j], v);
#pragma unroll
        for (int k = 0; k < 16; ++k) v = fmaf(xv[k], srw[k*16+j], v);
        o[j] = v > 0.f ? v : 0.f;
    }
    float4* op = reinterpret_cast<float4*>(X + (size_t)node * 16);
#pragma unroll
    for (int qq = 0; qq < 4; ++qq)
        op[qq] = make_float4(o[qq*4+0], o[qq*4+1], o[qq*4+2], o[qq*4+3]);
    float gg = 0.f;
#pragma unroll
    for (int j = 0; j < 16; ++j) {
        float u = sp3b[j];
#pragma unroll
        for (int k = 0; k < 16; ++k) u = fmaf(o[k], sp3w[k*16+j], u);
        u = u > 0.f ? u : 0.f;
        gg = fmaf(u, sl3w[j], gg);
    }
    g[node] = __float2half(gg);
}

__global__ __launch_bounds__(512, 8) void layer3_kernel(
    const int* __restrict__ counts, const unsigned int* __restrict__ sorted,
    const __half* __restrict__ g, const float* __restrict__ X,
    const float* __restrict__ l3b, const float* __restrict__ r3w,
    float* __restrict__ out)
{
    __shared__ float acc[256];
    __shared__ float srw[16];
    __shared__ float sb;
    int t = threadIdx.x, b = blockIdx.x;
    if (t < 256) acc[t] = 0.f;
    if (t < 16) srw[t] = r3w[t];
    if (t == 0) sb = l3b[0];
    __syncthreads();
    int beg = counts[(b * SB) * NBP];
    int end = (b == K_B - 1) ? NE : counts[((b + 1) * SB) * NBP];
    int a0 = beg & ~3;
    for (int c = a0 + t * 4; c < end; c += 2048) {
        uint4 sv = *reinterpret_cast<const uint4*>(sorted + c);
        const unsigned* svp = &sv.x;
        __half gr[4]; int dl[4]; bool ok[4];
#pragma unroll
        for (int j = 0; j < 4; ++j) {
            int e = c + j;
            unsigned v = svp[j];
            ok[j] = (e >= beg) && (e < end);
            int s = ok[j] ? (int)(v & 0xFFFFFu) : 0;
            dl[j] = (int)(v >> 20);
            gr[j] = g[s];
        }
#pragma unroll
        for (int j = 0; j < 4; ++j) if (ok[j])
            atomicAdd(&acc[dl[j]], __half2float(gr[j]));
    }
    __syncthreads();
    if (t >= 256) return;
    int node = (b << 8) + t;
    if (node >= NN) return;
    float val = acc[t] + sb;
    const float4* xp = reinterpret_cast<const float4*>(X + (size_t)node * 16);
#pragma unroll
    for (int qq = 0; qq < 4; ++qq) {
        float4 u = xp[qq];
        val = fmaf(u.x, srw[qq*4+0], val);
        val = fmaf(u.y, srw[qq*4+1], val);
        val = fmaf(u.z, srw[qq*4+2], val);
        val = fmaf(u.w, srw[qq*4+3], val);
    }
    out[node] = 1.f / (1.f + expf(-val));
}

// ================= launch =================

extern "C" void kernel_launch(void* const* d_in, const int* in_sizes, int n_in,
                              void* d_out, int out_size, void* d_ws, size_t ws_size,
                              hipStream_t stream) {
    const float* x   = (const float*)d_in[0];
    const int*   ei  = (const int*)d_in[1];
    const float* p1w = (const float*)d_in[2];
    const float* p1b = (const float*)d_in[3];
    const float* l1w = (const float*)d_in[4];
    const float* l1b = (const float*)d_in[5];
    const float* r1w = (const float*)d_in[6];
    const float* p2w = (const float*)d_in[7];
    const float* p2b = (const float*)d_in[8];
    const float* l2w = (const float*)d_in[9];
    const float* l2b = (const float*)d_in[10];
    const float* r2w = (const float*)d_in[11];
    const float* p3w = (const float*)d_in[12];
    const float* p3b = (const float*)d_in[13];
    const float* l3w = (const float*)d_in[14];
    const float* l3b = (const float*)d_in[15];
    const float* r3w = (const float*)d_in[16];
    float* out = (float*)d_out;

    char* ws = (char*)d_ws;
    float*        X      = (float*)(ws);                   // 32,000,000  x2/x3 (f32)
    __half*       H2     = (__half*)(ws + 32000000);       // 16,000,000  h2 fp16
    unsigned int* sorted = (unsigned int*)(ws + 48000000); // 20,000,000  packed edges
    __half*       h1     = (__half*)(ws + 68000000);       //  4,000,000  h1 fp16
    __half*       g      = (__half*)(ws + 72000000);       //  1,000,000  g fp16
    int*          counts = (int*)(ws + 73000000);          // 15,646,720  (M_PAD ints)
    int*          partial= (int*)(ws + 88646720);          //  3,820

    const int nbN = (NN + 255) / 256;   // 1954

    // ---- single-pass partition by (dst_bucket, src_bin) ----
    hipMemsetAsync(counts, 0, (size_t)M_PAD * sizeof(int), stream);
    pass1_count<<<NBP, 1024, 0, stream>>>(ei, counts);
    scan_reduce<<<NB_SC, 256, 0, stream>>>(counts, partial);
    scan_mid<<<1, 256, 0, stream>>>(partial);
    scan_apply<<<NB_SC, 256, 0, stream>>>(counts, partial);
    pass2_scatter<<<NBP, 1024, 0, stream>>>(ei, counts, sorted);

    // ---- layers ----
    proj1<<<nbN, 256, 0, stream>>>(x, p1w, p1b, h1);
    layer1_kernel<<<K_B, 512, 0, stream>>>(counts, sorted, h1, x,
                                           l1w, l1b, r1w, p2w, p2b, X, H2);
    layer2_kernel<<<K_B, 512, 0, stream>>>(counts, sorted, H2, X,
                                           l2w, l2b, r2w, p3w, p3b, l3w, g);
    layer3_kernel<<<K_B, 512, 0, stream>>>(counts, sorted, g, X, l3b, r3w, out);
}

// Round 6
// 439.012 us; speedup vs baseline: 1.9350x; 1.9350x over previous
//
#include <hip/hip_runtime.h>
#include <hip/hip_fp16.h>
#include <math.h>

#define NN 500000
#define NE 5000000
#define K_B 1954                  // dst buckets of 256 nodes
#define NBP 500                   // partition blocks
#define EPB 10000                 // edges per partition block (NBP*EPB == NE)
#define M_SCAN (K_B * NBP)        // 977000
#define SC_CH 4096                // scan chunk: 256 thr * 16
#define NB_SC 239                 // ceil(M_SCAN / SC_CH)
#define M_PAD (NB_SC * SC_CH)     // 978944
#define CAP 6144                  // max edges per bucket staged in LDS (mean 2560, sd ~51)

__device__ inline float2 cvt2(unsigned u) {
    __half2 h = *reinterpret_cast<const __half2*>(&u);
    return __half22float2(h);
}

// ================= bucket partition (round-3 proven, no global atomics) =================

__global__ __launch_bounds__(256) void pass1_count(
    const int* __restrict__ ei, int* __restrict__ counts)
{
    __shared__ int lh[K_B];
    for (int i = threadIdx.x; i < K_B; i += 256) lh[i] = 0;
    __syncthreads();
    int e0 = blockIdx.x * EPB;
    for (int k = threadIdx.x; k < EPB; k += 256) {
        int d = ei[NE + e0 + k];
        atomicAdd(&lh[d >> 8], 1);
    }
    __syncthreads();
    for (int i = threadIdx.x; i < K_B; i += 256)
        counts[i * NBP + blockIdx.x] = lh[i];
}

__global__ __launch_bounds__(256) void scan_reduce(
    const int* __restrict__ a, int* __restrict__ partial)
{
    __shared__ int sm[256];
    int base = blockIdx.x * SC_CH + threadIdx.x * 16;
    int s = 0;
#pragma unroll
    for (int k = 0; k < 16; ++k) s += a[base + k];
    sm[threadIdx.x] = s;
    __syncthreads();
    for (int off = 128; off > 0; off >>= 1) {
        if (threadIdx.x < off) sm[threadIdx.x] += sm[threadIdx.x + off];
        __syncthreads();
    }
    if (threadIdx.x == 0) partial[blockIdx.x] = sm[0];
}

__global__ __launch_bounds__(256) void scan_mid(int* __restrict__ partial)
{
    __shared__ int sm[256];
    int t = threadIdx.x;
    int orig = (t < NB_SC) ? partial[t] : 0;
    sm[t] = orig;
    __syncthreads();
    for (int off = 1; off < 256; off <<= 1) {
        int v = (t >= off) ? sm[t - off] : 0;
        __syncthreads();
        sm[t] += v;
        __syncthreads();
    }
    if (t < NB_SC) partial[t] = sm[t] - orig;   // exclusive
}

__global__ __launch_bounds__(256) void scan_apply(
    int* __restrict__ a, const int* __restrict__ partial)
{
    __shared__ int sm[256];
    int b = blockIdx.x, t = threadIdx.x;
    int base = b * SC_CH + t * 16;
    int v[16]; int s = 0;
#pragma unroll
    for (int k = 0; k < 16; ++k) { v[k] = a[base + k]; s += v[k]; }
    sm[t] = s;
    __syncthreads();
    int orig = s;
    for (int off = 1; off < 256; off <<= 1) {
        int u = (t >= off) ? sm[t - off] : 0;
        __syncthreads();
        sm[t] += u;
        __syncthreads();
    }
    int run = partial[b] + sm[t] - orig;
#pragma unroll
    for (int k = 0; k < 16; ++k) { a[base + k] = run; run += v[k]; }
}

__global__ __launch_bounds__(256) void pass2_scatter(
    const int* __restrict__ ei, const int* __restrict__ counts,
    unsigned int* __restrict__ edg)
{
    __shared__ int cur[K_B];
    for (int i = threadIdx.x; i < K_B; i += 256)
        cur[i] = counts[i * NBP + blockIdx.x];
    __syncthreads();
    int e0 = blockIdx.x * EPB;
    for (int k = threadIdx.x; k < EPB; k += 256) {
        int e = e0 + k;
        int s = ei[e];
        int d = ei[NE + e];
        int bin = d >> 8;
        int pos = atomicAdd(&cur[bin], 1);   // LDS atomic
        edg[pos] = ((unsigned)(d & 255) << 20) | (unsigned)s;
    }
}

// ===== per-bucket counting sort -> full dst-sorted src list (in place) + rowptr =====

__global__ __launch_bounds__(256) void csr_finalize(
    const int* __restrict__ counts, unsigned int* __restrict__ edg,
    int* __restrict__ rowptr)
{
    __shared__ unsigned ebuf[CAP];
    __shared__ int cnt[256];
    __shared__ int cs[256];
    int b = blockIdx.x, t = threadIdx.x;
    int beg = counts[b * NBP];
    int end = (b == K_B - 1) ? NE : counts[(b + 1) * NBP];
    int n = end - beg;
    if (n > CAP) n = CAP;   // statistically impossible for this data
    cnt[t] = 0;
    __syncthreads();
    for (int k = t; k < n; k += 256) {
        unsigned v = edg[beg + k];
        ebuf[k] = v;
        atomicAdd(&cnt[v >> 20], 1);
    }
    __syncthreads();
    cs[t] = cnt[t];
    __syncthreads();
    for (int off = 1; off < 256; off <<= 1) {
        int u = (t >= off) ? cs[t - off] : 0;
        __syncthreads();
        cs[t] += u;
        __syncthreads();
    }
    int excl = cs[t] - cnt[t];
    int node = (b << 8) + t;
    if (node < NN) rowptr[node] = beg + excl;
    if (b == K_B - 1 && t == 0) rowptr[NN] = NE;
    cnt[t] = excl;          // becomes cursor
    __syncthreads();
    for (int k = t; k < n; k += 256) {
        unsigned v = ebuf[k];
        int pos = atomicAdd(&cnt[v >> 20], 1);   // LDS atomic
        edg[beg + pos] = v & 0xFFFFFu;           // plain src index
    }
}

// ================= node-side projection (fp16 output) =================

__global__ __launch_bounds__(256) void proj1(
    const float* __restrict__ x, const float* __restrict__ w,
    const float* __restrict__ b, __half* __restrict__ h1)
{
    int i = blockIdx.x * 256 + threadIdx.x;
    if (i >= NN) return;
    float x0 = x[i*3+0], x1 = x[i*3+1], x2 = x[i*3+2];
    __half hh[4];
#pragma unroll
    for (int j = 0; j < 3; ++j) {
        float v = fmaf(x0, w[0*3+j], fmaf(x1, w[1*3+j], fmaf(x2, w[2*3+j], b[j])));
        hh[j] = __float2half(v > 0.f ? v : 0.f);
    }
    hh[3] = __float2half(0.f);
    *reinterpret_cast<uint2*>(h1 + (size_t)i * 4) = *reinterpret_cast<uint2*>(hh);
}

// ================= layers: node-major, 1 thread/node, register accumulate =================

__global__ __launch_bounds__(256) void layer1_kernel(
    const int* __restrict__ rowptr, const unsigned int* __restrict__ edg,
    const __half* __restrict__ h1, const float* __restrict__ x,
    const float* __restrict__ l1w, const float* __restrict__ l1b,
    const float* __restrict__ r1w,
    const float* __restrict__ p2w, const float* __restrict__ p2b,
    float* __restrict__ X2, __half* __restrict__ H2)
{
    __shared__ float slw[48], srw[48], slb[16], sp2w[256], sp2b[16];
    int t = threadIdx.x;
    sp2w[t] = p2w[t];
    if (t < 48) { slw[t] = l1w[t]; srw[t] = r1w[t]; }
    if (t < 16) { slb[t] = l1b[t]; sp2b[t] = p2b[t]; }
    __syncthreads();
    int i = blockIdx.x * 256 + t;
    if (i >= NN) return;
    int beg = rowptr[i], end = rowptr[i+1];
    float a0 = 0.f, a1 = 0.f, a2 = 0.f;
    int e = beg;
    for (; e + 1 < end; e += 2) {
        int s0 = (int)edg[e], s1 = (int)edg[e+1];
        uint2 r0 = *reinterpret_cast<const uint2*>(h1 + (size_t)s0 * 4);
        uint2 r1 = *reinterpret_cast<const uint2*>(h1 + (size_t)s1 * 4);
        float2 p0 = cvt2(r0.x), q0 = cvt2(r0.y);
        float2 p1 = cvt2(r1.x), q1 = cvt2(r1.y);
        a0 += p0.x + p1.x; a1 += p0.y + p1.y; a2 += q0.x + q1.x;
    }
    if (e < end) {
        int s0 = (int)edg[e];
        uint2 r0 = *reinterpret_cast<const uint2*>(h1 + (size_t)s0 * 4);
        float2 p0 = cvt2(r0.x), q0 = cvt2(r0.y);
        a0 += p0.x; a1 += p0.y; a2 += q0.x;
    }
    float x0 = x[i*3+0], x1 = x[i*3+1], x2v = x[i*3+2];
    float h[16];
#pragma unroll
    for (int j = 0; j < 16; ++j) {
        float v = slb[j];
        v = fmaf(a0, slw[j], fmaf(a1, slw[16+j], fmaf(a2, slw[32+j], v)));
        v = fmaf(x0, srw[j], fmaf(x1, srw[16+j], fmaf(x2v, srw[32+j], v)));
        h[j] = v > 0.f ? v : 0.f;
    }
    float4* xp = reinterpret_cast<float4*>(X2 + (size_t)i * 16);
#pragma unroll
    for (int q = 0; q < 4; ++q)
        xp[q] = make_float4(h[q*4+0], h[q*4+1], h[q*4+2], h[q*4+3]);
    __half hh[16];
#pragma unroll
    for (int j = 0; j < 16; ++j) {
        float v = sp2b[j];
#pragma unroll
        for (int k = 0; k < 16; ++k) v = fmaf(h[k], sp2w[k*16+j], v);
        hh[j] = __float2half(v > 0.f ? v : 0.f);
    }
    uint4* hp = reinterpret_cast<uint4*>(H2 + (size_t)i * 16);
    hp[0] = reinterpret_cast<uint4*>(hh)[0];
    hp[1] = reinterpret_cast<uint4*>(hh)[1];
}

__global__ __launch_bounds__(256) void layer2_kernel(
    const int* __restrict__ rowptr, const unsigned int* __restrict__ edg,
    const __half* __restrict__ H2, float* X /* x2 in, x3 out */,
    const float* __restrict__ l2w, const float* __restrict__ l2b,
    const float* __restrict__ r2w,
    const float* __restrict__ p3w, const float* __restrict__ p3b,
    const float* __restrict__ l3w, __half* __restrict__ g)
{
    __shared__ float slw[256], srw[256], sp3w[256];
    __shared__ float slb[16], sp3b[16], sl3w[16];
    int t = threadIdx.x;
    slw[t] = l2w[t]; srw[t] = r2w[t]; sp3w[t] = p3w[t];
    if (t < 16) { slb[t] = l2b[t]; sp3b[t] = p3b[t]; sl3w[t] = l3w[t]; }
    __syncthreads();
    int i = blockIdx.x * 256 + t;
    if (i >= NN) return;
    int beg = rowptr[i], end = rowptr[i+1];
    float av[16];
#pragma unroll
    for (int k = 0; k < 16; ++k) av[k] = 0.f;
    int e = beg;
    for (; e + 1 < end; e += 2) {
        int s0 = (int)edg[e], s1 = (int)edg[e+1];
        const uint4* r0 = reinterpret_cast<const uint4*>(H2 + (size_t)s0 * 16);
        const uint4* r1 = reinterpret_cast<const uint4*>(H2 + (size_t)s1 * 16);
        uint4 A0 = r0[0], B0 = r0[1];
        uint4 A1 = r1[0], B1 = r1[1];
        float2 f;
        f = cvt2(A0.x); av[0] += f.x; av[1] += f.y;
        f = cvt2(A0.y); av[2] += f.x; av[3] += f.y;
        f = cvt2(A0.z); av[4] += f.x; av[5] += f.y;
        f = cvt2(A0.w); av[6] += f.x; av[7] += f.y;
        f = cvt2(B0.x); av[8] += f.x; av[9] += f.y;
        f = cvt2(B0.y); av[10] += f.x; av[11] += f.y;
        f = cvt2(B0.z); av[12] += f.x; av[13] += f.y;
        f = cvt2(B0.w); av[14] += f.x; av[15] += f.y;
        f = cvt2(A1.x); av[0] += f.x; av[1] += f.y;
        f = cvt2(A1.y); av[2] += f.x; av[3] += f.y;
        f = cvt2(A1.z); av[4] += f.x; av[5] += f.y;
        f = cvt2(A1.w); av[6] += f.x; av[7] += f.y;
        f = cvt2(B1.x); av[8] += f.x; av[9] += f.y;
        f = cvt2(B1.y); av[10] += f.x; av[11] += f.y;
        f = cvt2(B1.z); av[12] += f.x; av[13] += f.y;
        f = cvt2(B1.w); av[14] += f.x; av[15] += f.y;
    }
    if (e < end) {
        int s0 = (int)edg[e];
        const uint4* r0 = reinterpret_cast<const uint4*>(H2 + (size_t)s0 * 16);
        uint4 A0 = r0[0], B0 = r0[1];
        float2 f;
        f = cvt2(A0.x); av[0] += f.x; av[1] += f.y;
        f = cvt2(A0.y); av[2] += f.x; av[3] += f.y;
        f = cvt2(A0.z); av[4] += f.x; av[5] += f.y;
        f = cvt2(A0.w); av[6] += f.x; av[7] += f.y;
        f = cvt2(B0.x); av[8] += f.x; av[9] += f.y;
        f = cvt2(B0.y); av[10] += f.x; av[11] += f.y;
        f = cvt2(B0.z); av[12] += f.x; av[13] += f.y;
        f = cvt2(B0.w); av[14] += f.x; av[15] += f.y;
    }
    float xv[16];
    const float4* xp = reinterpret_cast<const float4*>(X + (size_t)i * 16);
#pragma unroll
    for (int q = 0; q < 4; ++q) {
        float4 u = xp[q];
        xv[q*4+0] = u.x; xv[q*4+1] = u.y; xv[q*4+2] = u.z; xv[q*4+3] = u.w;
    }
    float o[16];
#pragma unroll
    for (int j = 0; j < 16; ++j) {
        float v = slb[j];
#pragma unroll
        for (int k = 0; k < 16; ++k) v = fmaf(av[k], slw[k*16+j], v);
#pragma unroll
        for (int k = 0; k < 16; ++k) v = fmaf(xv[k], srw[k*16+j], v);
        o[j] = v > 0.f ? v : 0.f;
    }
    float4* op = reinterpret_cast<float4*>(X + (size_t)i * 16);
#pragma unroll
    for (int q = 0; q < 4; ++q)
        op[q] = make_float4(o[q*4+0], o[q*4+1], o[q*4+2], o[q*4+3]);
    float gg = 0.f;
#pragma unroll
    for (int j = 0; j < 16; ++j) {
        float u = sp3b[j];
#pragma unroll
        for (int k = 0; k < 16; ++k) u = fmaf(o[k], sp3w[k*16+j], u);
        u = u > 0.f ? u : 0.f;
        gg = fmaf(u, sl3w[j], gg);
    }
    g[i] = __float2half(gg);
}

__global__ __launch_bounds__(256) void layer3_kernel(
    const int* __restrict__ rowptr, const unsigned int* __restrict__ edg,
    const __half* __restrict__ g, const float* __restrict__ X,
    const float* __restrict__ l3b, const float* __restrict__ r3w,
    float* __restrict__ out)
{
    __shared__ float srw[16];
    __shared__ float sb;
    int t = threadIdx.x;
    if (t < 16) srw[t] = r3w[t];
    if (t == 0) sb = l3b[0];
    __syncthreads();
    int i = blockIdx.x * 256 + t;
    if (i >= NN) return;
    int beg = rowptr[i], end = rowptr[i+1];
    float a = 0.f;
    int e = beg;
    for (; e + 1 < end; e += 2) {
        int s0 = (int)edg[e], s1 = (int)edg[e+1];
        __half g0 = g[s0], g1 = g[s1];
        a += __half2float(g0) + __half2float(g1);
    }
    if (e < end) a += __half2float(g[(int)edg[e]]);
    float val = a + sb;
    const float4* xp = reinterpret_cast<const float4*>(X + (size_t)i * 16);
#pragma unroll
    for (int q = 0; q < 4; ++q) {
        float4 u = xp[q];
        val = fmaf(u.x, srw[q*4+0], val);
        val = fmaf(u.y, srw[q*4+1], val);
        val = fmaf(u.z, srw[q*4+2], val);
        val = fmaf(u.w, srw[q*4+3], val);
    }
    out[i] = 1.f / (1.f + expf(-val));
}

// ================= launch =================

extern "C" void kernel_launch(void* const* d_in, const int* in_sizes, int n_in,
                              void* d_out, int out_size, void* d_ws, size_t ws_size,
                              hipStream_t stream) {
    const float* x   = (const float*)d_in[0];
    const int*   ei  = (const int*)d_in[1];
    const float* p1w = (const float*)d_in[2];
    const float* p1b = (const float*)d_in[3];
    const float* l1w = (const float*)d_in[4];
    const float* l1b = (const float*)d_in[5];
    const float* r1w = (const float*)d_in[6];
    const float* p2w = (const float*)d_in[7];
    const float* p2b = (const float*)d_in[8];
    const float* l2w = (const float*)d_in[9];
    const float* l2b = (const float*)d_in[10];
    const float* r2w = (const float*)d_in[11];
    const float* p3w = (const float*)d_in[12];
    const float* p3b = (const float*)d_in[13];
    const float* l3w = (const float*)d_in[14];
    const float* l3b = (const float*)d_in[15];
    const float* r3w = (const float*)d_in[16];
    float* out = (float*)d_out;

    char* ws = (char*)d_ws;
    float*        X      = (float*)(ws);                   // 32,000,000  x2/x3 (f32)
    __half*       H2     = (__half*)(ws + 32000000);       // 16,000,000  h2 fp16
    unsigned int* edg    = (unsigned int*)(ws + 48000000); // 20,000,000  packed -> src csr
    __half*       h1     = (__half*)(ws + 68000000);       //  4,000,000  h1 fp16
    __half*       g      = (__half*)(ws + 72000000);       //  1,000,000  g fp16
    int*          rowptr = (int*)(ws + 73000000);          //  2,000,004
    int*          counts = (int*)(ws + 75000016);          //  3,915,776  (M_PAD ints)
    int*          partial= (int*)(ws + 78915800);          //  956

    const int nbN = (NN + 255) / 256;   // 1954

    // ---- partition by dst bucket, then per-bucket counting sort -> CSR ----
    hipMemsetAsync(counts, 0, (size_t)M_PAD * sizeof(int), stream);
    pass1_count<<<NBP, 256, 0, stream>>>(ei, counts);
    scan_reduce<<<NB_SC, 256, 0, stream>>>(counts, partial);
    scan_mid<<<1, 256, 0, stream>>>(partial);
    scan_apply<<<NB_SC, 256, 0, stream>>>(counts, partial);
    pass2_scatter<<<NBP, 256, 0, stream>>>(ei, counts, edg);
    csr_finalize<<<K_B, 256, 0, stream>>>(counts, edg, rowptr);

    // ---- layers: node-major, register accumulate, fused epilogues ----
    proj1<<<nbN, 256, 0, stream>>>(x, p1w, p1b, h1);
    layer1_kernel<<<nbN, 256, 0, stream>>>(rowptr, edg, h1, x,
                                           l1w, l1b, r1w, p2w, p2b, X, H2);
    layer2_kernel<<<nbN, 256, 0, stream>>>(rowptr, edg, H2, X,
                                           l2w, l2b, r2w, p3w, p3b, l3w, g);
    layer3_kernel<<<nbN, 256, 0, stream>>>(rowptr, edg, g, X, l3b, r3w, out);
}